// Round 1
// baseline (349.231 us; speedup 1.0000x reference)
//
#include <hip/hip_runtime.h>
#include <hip/hip_bf16.h>

// Problem constants
#define BATCH 4
#define TSEQ  2048
#define CDIM  768
#define HNUM  12
#define DHEAD 64
#define NQKV  (3*CDIM)          // 2304
#define BTOT  (BATCH*TSEQ)      // 8192
#define BH    (BATCH*HNUM)      // 48

typedef unsigned short u16;
typedef __attribute__((ext_vector_type(8))) __bf16 bf16x8;
typedef __attribute__((ext_vector_type(4))) float f32x4;

#define MFMA16(a,b,c) __builtin_amdgcn_mfma_f32_16x16x32_bf16((a),(b),(c),0,0,0)

// fp32 -> bf16 RNE (hand-rolled, version-independent)
__device__ __forceinline__ u16 f2b(float f) {
    union { float f; unsigned u; } v; v.f = f;
    unsigned u = v.u;
    unsigned r = (u + 0x7fffu + ((u >> 16) & 1u)) >> 16;
    return (u16)r;
}

__device__ __forceinline__ void gload_lds(const void* g, void* l) {
    __builtin_amdgcn_global_load_lds(
        (const __attribute__((address_space(1))) void*)g,
        (__attribute__((address_space(3))) void*)l, 16, 0, 0);
}

// ---------------- elementwise cast fp32 -> bf16 ----------------
__global__ __launch_bounds__(256) void cast_f32_bf16(
        const float* __restrict__ in, u16* __restrict__ out, int n4) {
    int i = blockIdx.x * blockDim.x + threadIdx.x;
    if (i >= n4) return;
    float4 a = reinterpret_cast<const float4*>(in)[i];
    ushort4 o;
    o.x = f2b(a.x); o.y = f2b(a.y); o.z = f2b(a.z); o.w = f2b(a.w);
    reinterpret_cast<ushort4*>(out)[i] = o;
}

// ---------------- transpose + cast: in[R][Cc] fp32 -> out[Cc][R] bf16 ----------------
__global__ __launch_bounds__(256) void tcast(
        const float* __restrict__ in, u16* __restrict__ out, int R, int Cc) {
    __shared__ float tile[32][33];
    int c0 = blockIdx.x * 32, r0 = blockIdx.y * 32;
    int tx = threadIdx.x, ty = threadIdx.y;   // block (32,8)
    #pragma unroll
    for (int i = 0; i < 32; i += 8)
        tile[ty + i][tx] = in[(size_t)(r0 + ty + i) * Cc + c0 + tx];
    __syncthreads();
    #pragma unroll
    for (int i = 0; i < 32; i += 8)
        out[(size_t)(c0 + ty + i) * R + r0 + tx] = f2b(tile[tx][ty + i]);
}

// ---------------- GEMM: C[M x N] = A[M x K] * Bt[N x K]^T (+bias) ----------------
// MODE 0: qkv projection -> scatter to q(bf16,[B,H,T,D], pre-scaled 0.125),
//                           k(bf16,[B,H,T,D]), vT(bf16,[B,H,D,T])
// MODE 1: out projection -> fp32 [BTOT, CDIM]
template<int MODE>
__global__ __launch_bounds__(256) void gemm_bt(
        const u16* __restrict__ A, const u16* __restrict__ Bt,
        const float* __restrict__ bias,
        u16* __restrict__ qb, u16* __restrict__ kb, u16* __restrict__ vtb,
        float* __restrict__ outf, int M, int N, int K) {
    __shared__ u16 sA[2][128 * 32];
    __shared__ u16 sB[2][128 * 32];
    const int tid = threadIdx.x;
    const int lane = tid & 63;
    const int w = tid >> 6;
    const int wr = w >> 1, wc = w & 1;          // 64x64 quadrant per wave
    const int m0 = blockIdx.y * 128, n0 = blockIdx.x * 128;

    f32x4 acc[4][4] = {};

    auto stage = [&](int buf, int kt) {
        #pragma unroll
        for (int i = 0; i < 2; ++i) {
            int chunk = i * 256 + tid;          // 512 chunks of 8 bf16
            int row = chunk >> 2, c8 = chunk & 3;
            gload_lds(A  + (size_t)(m0 + row) * K + kt * 32 + c8 * 8, &sA[buf][chunk * 8]);
            gload_lds(Bt + (size_t)(n0 + row) * K + kt * 32 + c8 * 8, &sB[buf][chunk * 8]);
        }
    };

    const int KT = K / 32;
    stage(0, 0);
    __syncthreads();
    for (int kt = 0; kt < KT; ++kt) {
        if (kt + 1 < KT) stage((kt + 1) & 1, kt + 1);
        const u16* cA = sA[kt & 1];
        const u16* cB = sB[kt & 1];
        bf16x8 af[4], bfr[4];
        #pragma unroll
        for (int m = 0; m < 4; ++m)
            af[m] = *(const bf16x8*)&cA[(wr * 64 + m * 16 + (lane & 15)) * 32 + ((lane >> 4) << 3)];
        #pragma unroll
        for (int n = 0; n < 4; ++n)
            bfr[n] = *(const bf16x8*)&cB[(wc * 64 + n * 16 + (lane & 15)) * 32 + ((lane >> 4) << 3)];
        #pragma unroll
        for (int m = 0; m < 4; ++m)
            #pragma unroll
            for (int n = 0; n < 4; ++n)
                acc[m][n] = MFMA16(af[m], bfr[n], acc[m][n]);
        __syncthreads();
    }

    if (MODE == 0) {
        const int which = n0 / CDIM;            // 0=q 1=k 2=v, uniform per block
        #pragma unroll
        for (int m = 0; m < 4; ++m) {
            #pragma unroll
            for (int n = 0; n < 4; ++n) {
                const int cg = n0 + wc * 64 + n * 16 + (lane & 15);
                const int c  = cg - which * CDIM;
                const int h  = c >> 6, d = c & 63;
                const float bv = bias[cg];
                #pragma unroll
                for (int j = 0; j < 4; ++j) {
                    const int rg = m0 + wr * 64 + m * 16 + ((lane >> 4) << 2) + j;
                    const int b = rg >> 11, t = rg & (TSEQ - 1);
                    const float val = acc[m][n][j] + bv;
                    const size_t bh = (size_t)(b * HNUM + h);
                    if (which == 0)      qb[(bh * TSEQ + t) * DHEAD + d] = f2b(val * 0.125f);
                    else if (which == 1) kb[(bh * TSEQ + t) * DHEAD + d] = f2b(val);
                    else                 vtb[(bh * DHEAD + d) * TSEQ + t] = f2b(val);
                }
            }
        }
    } else {
        #pragma unroll
        for (int m = 0; m < 4; ++m) {
            #pragma unroll
            for (int n = 0; n < 4; ++n) {
                const int cg = n0 + wc * 64 + n * 16 + (lane & 15);
                const float bv = bias[cg];
                #pragma unroll
                for (int j = 0; j < 4; ++j) {
                    const int rg = m0 + wr * 64 + m * 16 + ((lane >> 4) << 2) + j;
                    outf[(size_t)rg * CDIM + cg] = acc[m][n][j] + bv;
                }
            }
        }
    }
}

// ---------------- causal flash attention ----------------
// grid: (16 q-tiles, 48 b*h). block 256 = 4 waves, each wave owns 32 q rows.
__global__ __launch_bounds__(256) void attn_fwd(
        const u16* __restrict__ qb, const u16* __restrict__ kb,
        const u16* __restrict__ vtb, u16* __restrict__ yb) {
    __shared__ u16 sK[128 * 64];    // [t][d]  (B^T form for S)
    __shared__ u16 sVt[64 * 128];   // [d][t]  (B^T form for PV)
    __shared__ u16 sP[128 * 128];   // bf16 P tile
    const int qt = blockIdx.x;
    const int bh = blockIdx.y;
    const int b = bh / HNUM, h = bh % HNUM;
    const int tid = threadIdx.x, lane = tid & 63, w = tid >> 6;
    const int q0 = qt * 128;
    const u16* qbase = qb  + (size_t)bh * TSEQ * DHEAD;
    const u16* kbase = kb  + (size_t)bh * TSEQ * DHEAD;
    const u16* vbase = vtb + (size_t)bh * DHEAD * TSEQ;

    // Q fragments held in registers for the whole block (scale pre-folded)
    bf16x8 qf[2][2];
    #pragma unroll
    for (int m = 0; m < 2; ++m)
        #pragma unroll
        for (int ks = 0; ks < 2; ++ks)
            qf[m][ks] = *(const bf16x8*)&qbase[(size_t)(q0 + w * 32 + m * 16 + (lane & 15)) * DHEAD
                                               + ks * 32 + ((lane >> 4) << 3)];

    f32x4 o[2][4] = {};
    float mrow[2][4], lrow[2][4];
    #pragma unroll
    for (int m = 0; m < 2; ++m)
        #pragma unroll
        for (int j = 0; j < 4; ++j) { mrow[m][j] = -__builtin_inff(); lrow[m][j] = 0.f; }

    for (int kt = 0; kt <= qt; ++kt) {
        const int k0 = kt * 128;
        // stage K tile (contiguous 16KB) and Vt tile ([64][T] rows)
        #pragma unroll
        for (int i = 0; i < 4; ++i) {
            int chunk = i * 256 + tid;          // 1024 chunks each
            gload_lds(kbase + (size_t)k0 * DHEAD + chunk * 8, &sK[chunk * 8]);
            int vrow = chunk >> 4, vc8 = chunk & 15;
            gload_lds(vbase + (size_t)vrow * TSEQ + k0 + vc8 * 8, &sVt[chunk * 8]);
        }
        __syncthreads();

        // S = Q K^T  (wave rows 32 x cols 128)
        f32x4 s[2][8] = {};
        #pragma unroll
        for (int n = 0; n < 8; ++n) {
            #pragma unroll
            for (int ks = 0; ks < 2; ++ks) {
                bf16x8 kf = *(const bf16x8*)&sK[(n * 16 + (lane & 15)) * 64 + ks * 32 + ((lane >> 4) << 3)];
                s[0][n] = MFMA16(qf[0][ks], kf, s[0][n]);
                s[1][n] = MFMA16(qf[1][ks], kf, s[1][n]);
            }
        }
        // causal mask on the diagonal tile
        if (kt == qt) {
            #pragma unroll
            for (int m = 0; m < 2; ++m)
                #pragma unroll
                for (int n = 0; n < 8; ++n)
                    #pragma unroll
                    for (int j = 0; j < 4; ++j) {
                        int rl = w * 32 + m * 16 + ((lane >> 4) << 2) + j;
                        int cl = n * 16 + (lane & 15);
                        if (cl > rl) s[m][n][j] = -__builtin_inff();
                    }
        }
        // online softmax (rows are wave-private; cols live on 16 lanes)
        #pragma unroll
        for (int m = 0; m < 2; ++m) {
            #pragma unroll
            for (int j = 0; j < 4; ++j) {
                float tmax = s[m][0][j];
                #pragma unroll
                for (int n = 1; n < 8; ++n) tmax = fmaxf(tmax, s[m][n][j]);
                tmax = fmaxf(tmax, __shfl_xor(tmax, 1));
                tmax = fmaxf(tmax, __shfl_xor(tmax, 2));
                tmax = fmaxf(tmax, __shfl_xor(tmax, 4));
                tmax = fmaxf(tmax, __shfl_xor(tmax, 8));
                float mnew = fmaxf(mrow[m][j], tmax);
                float sc = __expf(mrow[m][j] - mnew);
                mrow[m][j] = mnew;
                float rsum = 0.f;
                #pragma unroll
                for (int n = 0; n < 8; ++n) {
                    float p = __expf(s[m][n][j] - mnew);
                    s[m][n][j] = p;
                    rsum += p;
                }
                rsum += __shfl_xor(rsum, 1);
                rsum += __shfl_xor(rsum, 2);
                rsum += __shfl_xor(rsum, 4);
                rsum += __shfl_xor(rsum, 8);
                lrow[m][j] = lrow[m][j] * sc + rsum;
                #pragma unroll
                for (int n = 0; n < 4; ++n) o[m][n][j] *= sc;
            }
        }
        // write P (bf16) to LDS — wave-private rows
        #pragma unroll
        for (int m = 0; m < 2; ++m)
            #pragma unroll
            for (int n = 0; n < 8; ++n)
                #pragma unroll
                for (int j = 0; j < 4; ++j) {
                    int rl = w * 32 + m * 16 + ((lane >> 4) << 2) + j;
                    int cl = n * 16 + (lane & 15);
                    sP[rl * 128 + cl] = f2b(s[m][n][j]);
                }
        // PV: O += P[32 x 128] * V[128 x 64]
        #pragma unroll
        for (int ks = 0; ks < 4; ++ks) {
            bf16x8 pa[2];
            #pragma unroll
            for (int m = 0; m < 2; ++m)
                pa[m] = *(const bf16x8*)&sP[(w * 32 + m * 16 + (lane & 15)) * 128 + ks * 32 + ((lane >> 4) << 3)];
            #pragma unroll
            for (int n = 0; n < 4; ++n) {
                bf16x8 vf = *(const bf16x8*)&sVt[(n * 16 + (lane & 15)) * 128 + ks * 32 + ((lane >> 4) << 3)];
                o[0][n] = MFMA16(pa[0], vf, o[0][n]);
                o[1][n] = MFMA16(pa[1], vf, o[1][n]);
            }
        }
        __syncthreads();
    }

    // epilogue: y[b, t, h*64 + d] bf16
    #pragma unroll
    for (int m = 0; m < 2; ++m) {
        #pragma unroll
        for (int j = 0; j < 4; ++j) {
            const float inv = 1.f / lrow[m][j];
            const int t = q0 + w * 32 + m * 16 + ((lane >> 4) << 2) + j;
            #pragma unroll
            for (int n = 0; n < 4; ++n) {
                const int c = h * DHEAD + n * 16 + (lane & 15);
                yb[((size_t)b * TSEQ + t) * CDIM + c] = f2b(o[m][n][j] * inv);
            }
        }
    }
}

extern "C" void kernel_launch(void* const* d_in, const int* in_sizes, int n_in,
                              void* d_out, int out_size, void* d_ws, size_t ws_size,
                              hipStream_t stream) {
    const float* x      = (const float*)d_in[0];
    const float* W_attn = (const float*)d_in[1];
    const float* b_attn = (const float*)d_in[2];
    const float* W_proj = (const float*)d_in[3];
    const float* b_proj = (const float*)d_in[4];
    float* out = (float*)d_out;

    // workspace layout (bf16 = u16). yb aliases xb (xb dead after GEMM1).
    u16* ws = (u16*)d_ws;
    u16* xb     = ws;                                   // [BTOT][CDIM]
    u16* yb     = xb;                                   // [BTOT][CDIM] (alias)
    u16* WattnT = xb     + (size_t)BTOT * CDIM;         // [NQKV][CDIM]
    u16* WprojT = WattnT + (size_t)NQKV * CDIM;         // [CDIM][CDIM]
    u16* qb     = WprojT + (size_t)CDIM * CDIM;         // [BH][TSEQ][DHEAD]
    u16* kb     = qb     + (size_t)BH * TSEQ * DHEAD;
    u16* vtb    = kb     + (size_t)BH * TSEQ * DHEAD;   // [BH][DHEAD][TSEQ]

    // 1) casts / transposes
    int n4 = BTOT * CDIM / 4;
    cast_f32_bf16<<<(n4 + 255) / 256, 256, 0, stream>>>(x, xb, n4);
    tcast<<<dim3(NQKV / 32, CDIM / 32), dim3(32, 8), 0, stream>>>(W_attn, WattnT, CDIM, NQKV);
    tcast<<<dim3(CDIM / 32, CDIM / 32), dim3(32, 8), 0, stream>>>(W_proj, WprojT, CDIM, CDIM);

    // 2) QKV projection + scatter
    gemm_bt<0><<<dim3(NQKV / 128, BTOT / 128), 256, 0, stream>>>(
        xb, WattnT, b_attn, qb, kb, vtb, nullptr, BTOT, NQKV, CDIM);

    // 3) causal flash attention
    attn_fwd<<<dim3(TSEQ / 128, BH), 256, 0, stream>>>(qb, kb, vtb, yb);

    // 4) output projection
    gemm_bt<1><<<dim3(CDIM / 128, BTOT / 128), 256, 0, stream>>>(
        yb, WprojT, b_proj, nullptr, nullptr, nullptr, out, BTOT, CDIM, CDIM);
}

// Round 2
// 255.388 us; speedup vs baseline: 1.3675x; 1.3675x over previous
//
#include <hip/hip_runtime.h>
#include <hip/hip_bf16.h>

// Problem constants
#define BATCH 4
#define TSEQ  2048
#define CDIM  768
#define HNUM  12
#define DHEAD 64
#define NQKV  (3*CDIM)          // 2304
#define BTOT  (BATCH*TSEQ)      // 8192
#define BH    (BATCH*HNUM)      // 48

typedef unsigned short u16;
typedef __attribute__((ext_vector_type(8))) __bf16 bf16x8;
typedef __attribute__((ext_vector_type(4))) float f32x4;

#define MFMA16(a,b,c) __builtin_amdgcn_mfma_f32_16x16x32_bf16((a),(b),(c),0,0,0)

// fp32 -> bf16 RNE (hand-rolled, version-independent)
__device__ __forceinline__ u16 f2b(float f) {
    union { float f; unsigned u; } v; v.f = f;
    unsigned u = v.u;
    unsigned r = (u + 0x7fffu + ((u >> 16) & 1u)) >> 16;
    return (u16)r;
}

__device__ __forceinline__ void gload_lds(const void* g, void* l) {
    __builtin_amdgcn_global_load_lds(
        (const __attribute__((address_space(1))) void*)g,
        (__attribute__((address_space(3))) void*)l, 16, 0, 0);
}

// ---------------- elementwise cast fp32 -> bf16 ----------------
__global__ __launch_bounds__(256) void cast_f32_bf16(
        const float* __restrict__ in, u16* __restrict__ out, int n4) {
    int i = blockIdx.x * blockDim.x + threadIdx.x;
    if (i >= n4) return;
    float4 a = reinterpret_cast<const float4*>(in)[i];
    ushort4 o;
    o.x = f2b(a.x); o.y = f2b(a.y); o.z = f2b(a.z); o.w = f2b(a.w);
    reinterpret_cast<ushort4*>(out)[i] = o;
}

// ---------------- transpose + cast: in[R][Cc] fp32 -> out[Cc][R] bf16 ----------------
__global__ __launch_bounds__(256) void tcast(
        const float* __restrict__ in, u16* __restrict__ out, int R, int Cc) {
    __shared__ float tile[32][33];
    int c0 = blockIdx.x * 32, r0 = blockIdx.y * 32;
    int tx = threadIdx.x, ty = threadIdx.y;   // block (32,8)
    #pragma unroll
    for (int i = 0; i < 32; i += 8)
        tile[ty + i][tx] = in[(size_t)(r0 + ty + i) * Cc + c0 + tx];
    __syncthreads();
    #pragma unroll
    for (int i = 0; i < 32; i += 8)
        out[(size_t)(c0 + ty + i) * R + r0 + tx] = f2b(tile[tx][ty + i]);
}

// ---------------- GEMM: C[M x N] = A[M x K] * Bt[N x K]^T (+bias) ----------------
template<int MODE>
__global__ __launch_bounds__(256) void gemm_bt(
        const u16* __restrict__ A, const u16* __restrict__ Bt,
        const float* __restrict__ bias,
        u16* __restrict__ qb, u16* __restrict__ kb, u16* __restrict__ vtb,
        float* __restrict__ outf, int M, int N, int K) {
    __shared__ u16 sA[2][128 * 32];
    __shared__ u16 sB[2][128 * 32];
    const int tid = threadIdx.x;
    const int lane = tid & 63;
    const int w = tid >> 6;
    const int wr = w >> 1, wc = w & 1;          // 64x64 quadrant per wave
    const int m0 = blockIdx.y * 128, n0 = blockIdx.x * 128;

    f32x4 acc[4][4] = {};

    auto stage = [&](int buf, int kt) {
        #pragma unroll
        for (int i = 0; i < 2; ++i) {
            int chunk = i * 256 + tid;          // 512 chunks of 8 bf16
            int row = chunk >> 2, c8 = chunk & 3;
            gload_lds(A  + (size_t)(m0 + row) * K + kt * 32 + c8 * 8, &sA[buf][chunk * 8]);
            gload_lds(Bt + (size_t)(n0 + row) * K + kt * 32 + c8 * 8, &sB[buf][chunk * 8]);
        }
    };

    const int KT = K / 32;
    stage(0, 0);
    __syncthreads();
    for (int kt = 0; kt < KT; ++kt) {
        if (kt + 1 < KT) stage((kt + 1) & 1, kt + 1);
        const u16* cA = sA[kt & 1];
        const u16* cB = sB[kt & 1];
        bf16x8 af[4], bfr[4];
        #pragma unroll
        for (int m = 0; m < 4; ++m)
            af[m] = *(const bf16x8*)&cA[(wr * 64 + m * 16 + (lane & 15)) * 32 + ((lane >> 4) << 3)];
        #pragma unroll
        for (int n = 0; n < 4; ++n)
            bfr[n] = *(const bf16x8*)&cB[(wc * 64 + n * 16 + (lane & 15)) * 32 + ((lane >> 4) << 3)];
        #pragma unroll
        for (int m = 0; m < 4; ++m)
            #pragma unroll
            for (int n = 0; n < 4; ++n)
                acc[m][n] = MFMA16(af[m], bfr[n], acc[m][n]);
        __syncthreads();
    }

    if (MODE == 0) {
        const int which = n0 / CDIM;            // 0=q 1=k 2=v, uniform per block
        #pragma unroll
        for (int m = 0; m < 4; ++m) {
            #pragma unroll
            for (int n = 0; n < 4; ++n) {
                const int cg = n0 + wc * 64 + n * 16 + (lane & 15);
                const int c  = cg - which * CDIM;
                const int h  = c >> 6, d = c & 63;
                const float bv = bias[cg];
                #pragma unroll
                for (int j = 0; j < 4; ++j) {
                    const int rg = m0 + wr * 64 + m * 16 + ((lane >> 4) << 2) + j;
                    const int b = rg >> 11, t = rg & (TSEQ - 1);
                    const float val = acc[m][n][j] + bv;
                    const size_t bh = (size_t)(b * HNUM + h);
                    if (which == 0)      qb[(bh * TSEQ + t) * DHEAD + d] = f2b(val * 0.125f);
                    else if (which == 1) kb[(bh * TSEQ + t) * DHEAD + d] = f2b(val);
                    else                 vtb[(bh * DHEAD + d) * TSEQ + t] = f2b(val);
                }
            }
        }
    } else {
        #pragma unroll
        for (int m = 0; m < 4; ++m) {
            #pragma unroll
            for (int n = 0; n < 4; ++n) {
                const int cg = n0 + wc * 64 + n * 16 + (lane & 15);
                const float bv = bias[cg];
                #pragma unroll
                for (int j = 0; j < 4; ++j) {
                    const int rg = m0 + wr * 64 + m * 16 + ((lane >> 4) << 2) + j;
                    outf[(size_t)rg * CDIM + cg] = acc[m][n][j] + bv;
                }
            }
        }
    }
}

// ---------------- causal flash attention ----------------
// 1D grid of (TSEQ/64)*BH blocks, longest q-tiles dispatched FIRST (LPT).
// block 256 = 4 waves; wave owns 16 q rows. QBLK=64, KVBLK=128.
// LDS: sK [128][64] (swz128), sVt [64][128] (swz256), sP [64][128] (swz256) = 48KB.
__global__ __launch_bounds__(256) void attn_fwd(
        const u16* __restrict__ qb, const u16* __restrict__ kb,
        const u16* __restrict__ vtb, u16* __restrict__ yb) {
    __shared__ u16 sK[128 * 64];
    __shared__ u16 sVt[64 * 128];
    __shared__ u16 sP[64 * 128];
    const int NQT = TSEQ / 64;                   // 32 q-tiles
    const int qt = (NQT - 1) - (blockIdx.x / BH);
    const int bh = blockIdx.x % BH;
    const int b = bh / HNUM, h = bh % HNUM;
    const int tid = threadIdx.x, lane = tid & 63, w = tid >> 6;
    const int q0 = qt * 64;
    const u16* qbase = qb  + (size_t)bh * TSEQ * DHEAD;
    const u16* kbase = kb  + (size_t)bh * TSEQ * DHEAD;
    const u16* vbase = vtb + (size_t)bh * DHEAD * TSEQ;

    // Q fragments in registers (scale pre-folded into qb)
    bf16x8 qf[2];
    #pragma unroll
    for (int ks = 0; ks < 2; ++ks)
        qf[ks] = *(const bf16x8*)&qbase[(size_t)(q0 + w * 16 + (lane & 15)) * DHEAD
                                         + ks * 32 + ((lane >> 4) << 3)];

    f32x4 o[4] = {};
    float mrow[4], lrow[4];
    #pragma unroll
    for (int j = 0; j < 4; ++j) { mrow[j] = -__builtin_inff(); lrow[j] = 0.f; }

    const int nk = (q0 + 191) >> 7;              // #128-wide k tiles
    for (int kt = 0; kt < nk; ++kt) {
        const int k0 = kt << 7;
        const bool last = (kt == nk - 1);
        const bool hf = last && !(qt & 1);       // last tile only 64 cols valid

        if (kt) __syncthreads();                 // prev-iter LDS reads done
        // stage K [128][64] and Vt [64][128]; dest linear, SOURCE pre-swizzled
        #pragma unroll
        for (int i = 0; i < 4; ++i) {
            int p = (i * 256 + tid) << 4;        // physical byte offset (16B chunks)
            int lk = p ^ (((p >> 7) & 7) << 4);  // logical byte in [t][d] tile
            gload_lds(kbase + ((size_t)k0 << 6) + (lk >> 1), (char*)sK + p);
            int lv = p ^ (((p >> 8) & 7) << 4);  // logical byte in [d][t] tile
            gload_lds(vbase + (size_t)(lv >> 8) * TSEQ + k0 + ((lv & 255) >> 1),
                      (char*)sVt + p);
        }
        __syncthreads();                         // staging visible (vmcnt drained)

        // S = Q K^T  (wave: 16 rows x 128 cols)
        f32x4 s[8];
        #pragma unroll
        for (int n = 0; n < 8; ++n) s[n] = f32x4{0.f, 0.f, 0.f, 0.f};
        #pragma unroll
        for (int n = 0; n < 8; ++n) {
            if (!hf || n < 4) {
                #pragma unroll
                for (int ks = 0; ks < 2; ++ks) {
                    int r = n * 16 + (lane & 15);
                    int l = r * 128 + ks * 64 + ((lane >> 4) << 4);
                    bf16x8 kf = *(const bf16x8*)((const char*)sK + (l ^ ((r & 7) << 4)));
                    s[n] = MFMA16(qf[ks], kf, s[n]);
                }
            }
        }
        // causal mask (only the last k-tile can cross the diagonal)
        if (last) {
            const int rloc = w * 16 + ((lane >> 4) << 2);      // + j
            const int cloc = (lane & 15) + k0 - q0;            // + n*16
            #pragma unroll
            for (int n = 0; n < 8; ++n)
                if (!hf || n < 4) {
                    #pragma unroll
                    for (int j = 0; j < 4; ++j)
                        if (cloc + n * 16 > rloc + j) s[n][j] = -__builtin_inff();
                }
        }
        // online softmax (rows wave-private; 128 cols live on 16 lanes x 8 regs)
        #pragma unroll
        for (int j = 0; j < 4; ++j) {
            float tmax = -__builtin_inff();
            #pragma unroll
            for (int n = 0; n < 8; ++n)
                if (!hf || n < 4) tmax = fmaxf(tmax, s[n][j]);
            tmax = fmaxf(tmax, __shfl_xor(tmax, 1));
            tmax = fmaxf(tmax, __shfl_xor(tmax, 2));
            tmax = fmaxf(tmax, __shfl_xor(tmax, 4));
            tmax = fmaxf(tmax, __shfl_xor(tmax, 8));
            float mnew = fmaxf(mrow[j], tmax);
            float sc = __expf(mrow[j] - mnew);
            mrow[j] = mnew;
            float rsum = 0.f;
            #pragma unroll
            for (int n = 0; n < 8; ++n)
                if (!hf || n < 4) {
                    float p = __expf(s[n][j] - mnew);
                    s[n][j] = p;
                    rsum += p;
                }
            rsum += __shfl_xor(rsum, 1);
            rsum += __shfl_xor(rsum, 2);
            rsum += __shfl_xor(rsum, 4);
            rsum += __shfl_xor(rsum, 8);
            lrow[j] = lrow[j] * sc + rsum;
            #pragma unroll
            for (int n = 0; n < 4; ++n) o[n][j] *= sc;
        }
        // write P (bf16) to LDS — rows are wave-private, no barrier needed
        #pragma unroll
        for (int n = 0; n < 8; ++n)
            if (!hf || n < 4) {
                #pragma unroll
                for (int j = 0; j < 4; ++j) {
                    int rl = w * 16 + ((lane >> 4) << 2) + j;
                    int l = rl * 256 + (n * 16 + (lane & 15)) * 2;
                    *(u16*)((char*)sP + (l ^ ((rl & 7) << 4))) = f2b(s[n][j]);
                }
            }
        // PV: O += P[16 x 128] * V[128 x 64]
        #pragma unroll
        for (int ks = 0; ks < 4; ++ks) {
            if (!hf || ks < 2) {
                int rp = w * 16 + (lane & 15);
                int lp = rp * 256 + ks * 64 + ((lane >> 4) << 4);
                bf16x8 pa = *(const bf16x8*)((const char*)sP + (lp ^ ((rp & 7) << 4)));
                #pragma unroll
                for (int n = 0; n < 4; ++n) {
                    int d = n * 16 + (lane & 15);
                    int lv = d * 256 + ks * 64 + ((lane >> 4) << 4);
                    bf16x8 vf = *(const bf16x8*)((const char*)sVt + (lv ^ ((d & 7) << 4)));
                    o[n] = MFMA16(pa, vf, o[n]);
                }
            }
        }
    }

    // epilogue: y[b, t, h*64 + d] bf16
    #pragma unroll
    for (int j = 0; j < 4; ++j) {
        const float inv = 1.f / lrow[j];
        const int t = q0 + w * 16 + ((lane >> 4) << 2) + j;
        #pragma unroll
        for (int n = 0; n < 4; ++n) {
            const int c = h * DHEAD + n * 16 + (lane & 15);
            yb[((size_t)b * TSEQ + t) * CDIM + c] = f2b(o[n][j] * inv);
        }
    }
}

extern "C" void kernel_launch(void* const* d_in, const int* in_sizes, int n_in,
                              void* d_out, int out_size, void* d_ws, size_t ws_size,
                              hipStream_t stream) {
    const float* x      = (const float*)d_in[0];
    const float* W_attn = (const float*)d_in[1];
    const float* b_attn = (const float*)d_in[2];
    const float* W_proj = (const float*)d_in[3];
    const float* b_proj = (const float*)d_in[4];
    float* out = (float*)d_out;

    // workspace layout (bf16 = u16). yb aliases xb (xb dead after GEMM1).
    u16* ws = (u16*)d_ws;
    u16* xb     = ws;                                   // [BTOT][CDIM]
    u16* yb     = xb;                                   // [BTOT][CDIM] (alias)
    u16* WattnT = xb     + (size_t)BTOT * CDIM;         // [NQKV][CDIM]
    u16* WprojT = WattnT + (size_t)NQKV * CDIM;         // [CDIM][CDIM]
    u16* qb     = WprojT + (size_t)CDIM * CDIM;         // [BH][TSEQ][DHEAD]
    u16* kb     = qb     + (size_t)BH * TSEQ * DHEAD;
    u16* vtb    = kb     + (size_t)BH * TSEQ * DHEAD;   // [BH][DHEAD][TSEQ]

    // 1) casts / transposes
    int n4 = BTOT * CDIM / 4;
    cast_f32_bf16<<<(n4 + 255) / 256, 256, 0, stream>>>(x, xb, n4);
    tcast<<<dim3(NQKV / 32, CDIM / 32), dim3(32, 8), 0, stream>>>(W_attn, WattnT, CDIM, NQKV);
    tcast<<<dim3(CDIM / 32, CDIM / 32), dim3(32, 8), 0, stream>>>(W_proj, WprojT, CDIM, CDIM);

    // 2) QKV projection + scatter
    gemm_bt<0><<<dim3(NQKV / 128, BTOT / 128), 256, 0, stream>>>(
        xb, WattnT, b_attn, qb, kb, vtb, nullptr, BTOT, NQKV, CDIM);

    // 3) causal flash attention (longest-first 1D grid)
    attn_fwd<<<dim3((TSEQ / 64) * BH), 256, 0, stream>>>(qb, kb, vtb, yb);

    // 4) output projection
    gemm_bt<1><<<dim3(CDIM / 128, BTOT / 128), 256, 0, stream>>>(
        yb, WprojT, b_proj, nullptr, nullptr, nullptr, out, BTOT, CDIM, CDIM);
}

// Round 3
// 152.409 us; speedup vs baseline: 2.2914x; 1.6757x over previous
//
#include <hip/hip_runtime.h>
#include <hip/hip_bf16.h>

// Problem constants
#define BATCH 4
#define TSEQ  2048
#define CDIM  768
#define HNUM  12
#define DHEAD 64
#define NQKV  (3*CDIM)          // 2304
#define BTOT  (BATCH*TSEQ)      // 8192
#define BH    (BATCH*HNUM)      // 48

typedef unsigned short u16;
typedef __attribute__((ext_vector_type(8))) __bf16 bf16x8;
typedef __attribute__((ext_vector_type(4))) float f32x4;

#define MFMA16(a,b,c) __builtin_amdgcn_mfma_f32_16x16x32_bf16((a),(b),(c),0,0,0)

// fp32 -> bf16 RNE (hand-rolled, version-independent)
__device__ __forceinline__ u16 f2b(float f) {
    union { float f; unsigned u; } v; v.f = f;
    unsigned u = v.u;
    unsigned r = (u + 0x7fffu + ((u >> 16) & 1u)) >> 16;
    return (u16)r;
}

// pack 2 fp32 -> 2 bf16 in one u32 (lo -> bits 15:0), RNE
__device__ __forceinline__ unsigned cvtpk(float lo, float hi) {
    unsigned r;
    asm("v_cvt_pk_bf16_f32 %0, %1, %2" : "=v"(r) : "v"(lo), "v"(hi));
    return r;
}

__device__ __forceinline__ void gload_lds(const void* g, void* l) {
    __builtin_amdgcn_global_load_lds(
        (const __attribute__((address_space(1))) void*)g,
        (__attribute__((address_space(3))) void*)l, 16, 0, 0);
}

// ---------------- elementwise cast fp32 -> bf16 ----------------
__global__ __launch_bounds__(256) void cast_f32_bf16(
        const float* __restrict__ in, u16* __restrict__ out, int n4) {
    int i = blockIdx.x * blockDim.x + threadIdx.x;
    if (i >= n4) return;
    float4 a = reinterpret_cast<const float4*>(in)[i];
    ushort4 o;
    o.x = f2b(a.x); o.y = f2b(a.y); o.z = f2b(a.z); o.w = f2b(a.w);
    reinterpret_cast<ushort4*>(out)[i] = o;
}

// ---------------- transpose + cast: in[R][Cc] fp32 -> out[Cc][R] bf16 ----------------
__global__ __launch_bounds__(256) void tcast(
        const float* __restrict__ in, u16* __restrict__ out, int R, int Cc) {
    __shared__ float tile[32][33];
    int c0 = blockIdx.x * 32, r0 = blockIdx.y * 32;
    int tx = threadIdx.x, ty = threadIdx.y;   // block (32,8)
    #pragma unroll
    for (int i = 0; i < 32; i += 8)
        tile[ty + i][tx] = in[(size_t)(r0 + ty + i) * Cc + c0 + tx];
    __syncthreads();
    #pragma unroll
    for (int i = 0; i < 32; i += 8)
        out[(size_t)(c0 + ty + i) * R + r0 + tx] = f2b(tile[tx][ty + i]);
}

// ---------------- GEMM: C[M x N] = A[M x K] * Bt[N x K]^T (+bias) ----------------
template<int MODE>
__global__ __launch_bounds__(256) void gemm_bt(
        const u16* __restrict__ A, const u16* __restrict__ Bt,
        const float* __restrict__ bias,
        u16* __restrict__ qb, u16* __restrict__ kb, u16* __restrict__ vtb,
        float* __restrict__ outf, int M, int N, int K) {
    __shared__ u16 sA[2][128 * 32];
    __shared__ u16 sB[2][128 * 32];
    const int tid = threadIdx.x;
    const int lane = tid & 63;
    const int w = tid >> 6;
    const int wr = w >> 1, wc = w & 1;          // 64x64 quadrant per wave
    const int m0 = blockIdx.y * 128, n0 = blockIdx.x * 128;

    f32x4 acc[4][4] = {};

    auto stage = [&](int buf, int kt) {
        #pragma unroll
        for (int i = 0; i < 2; ++i) {
            int chunk = i * 256 + tid;          // 512 chunks of 8 bf16
            int row = chunk >> 2, c8 = chunk & 3;
            gload_lds(A  + (size_t)(m0 + row) * K + kt * 32 + c8 * 8, &sA[buf][chunk * 8]);
            gload_lds(Bt + (size_t)(n0 + row) * K + kt * 32 + c8 * 8, &sB[buf][chunk * 8]);
        }
    };

    const int KT = K / 32;
    stage(0, 0);
    __syncthreads();
    for (int kt = 0; kt < KT; ++kt) {
        if (kt + 1 < KT) stage((kt + 1) & 1, kt + 1);
        const u16* cA = sA[kt & 1];
        const u16* cB = sB[kt & 1];
        bf16x8 af[4], bfr[4];
        #pragma unroll
        for (int m = 0; m < 4; ++m)
            af[m] = *(const bf16x8*)&cA[(wr * 64 + m * 16 + (lane & 15)) * 32 + ((lane >> 4) << 3)];
        #pragma unroll
        for (int n = 0; n < 4; ++n)
            bfr[n] = *(const bf16x8*)&cB[(wc * 64 + n * 16 + (lane & 15)) * 32 + ((lane >> 4) << 3)];
        #pragma unroll
        for (int m = 0; m < 4; ++m)
            #pragma unroll
            for (int n = 0; n < 4; ++n)
                acc[m][n] = MFMA16(af[m], bfr[n], acc[m][n]);
        __syncthreads();
    }

    if (MODE == 0) {
        const int which = n0 / CDIM;            // 0=q 1=k 2=v, uniform per block
        #pragma unroll
        for (int m = 0; m < 4; ++m) {
            #pragma unroll
            for (int n = 0; n < 4; ++n) {
                const int cg = n0 + wc * 64 + n * 16 + (lane & 15);
                const int c  = cg - which * CDIM;
                const int h  = c >> 6, d = c & 63;
                const float bv = bias[cg];
                const int rg0 = m0 + wr * 64 + m * 16 + ((lane >> 4) << 2);
                const int b = rg0 >> 11, t0 = rg0 & (TSEQ - 1);
                const size_t bh = (size_t)(b * HNUM + h);
                if (which == 2) {
                    ushort4 pv;
                    pv.x = f2b(acc[m][n][0] + bv);
                    pv.y = f2b(acc[m][n][1] + bv);
                    pv.z = f2b(acc[m][n][2] + bv);
                    pv.w = f2b(acc[m][n][3] + bv);
                    *(ushort4*)&vtb[(bh * DHEAD + d) * TSEQ + t0] = pv;
                } else {
                    #pragma unroll
                    for (int j = 0; j < 4; ++j) {
                        const float val = acc[m][n][j] + bv;
                        if (which == 0) qb[(bh * TSEQ + t0 + j) * DHEAD + d] = f2b(val * 0.125f);
                        else            kb[(bh * TSEQ + t0 + j) * DHEAD + d] = f2b(val);
                    }
                }
            }
        }
    } else {
        #pragma unroll
        for (int m = 0; m < 4; ++m) {
            #pragma unroll
            for (int n = 0; n < 4; ++n) {
                const int cg = n0 + wc * 64 + n * 16 + (lane & 15);
                const float bv = bias[cg];
                #pragma unroll
                for (int j = 0; j < 4; ++j) {
                    const int rg = m0 + wr * 64 + m * 16 + ((lane >> 4) << 2) + j;
                    outf[(size_t)rg * CDIM + cg] = acc[m][n][j] + bv;
                }
            }
        }
    }
}

// ---------------- causal flash attention ----------------
// grid: (TSEQ/128)*BH blocks, longest q-tiles first. 512 threads = 8 waves,
// wave owns 16 q rows (QBLK=128). KVBLK=64, K/Vt double-buffered (4 x 8KB LDS).
// Swapped QK^T: S^T layout q=lane&15, k=n*16+g*4+j. P stays in registers
// (cvt_pk -> shfl redistribution to PV A-fragments). One barrier/iteration.
__global__ __launch_bounds__(512, 4) void attn_fwd(
        const u16* __restrict__ qb, const u16* __restrict__ kb,
        const u16* __restrict__ vtb, u16* __restrict__ yb) {
    __shared__ u16 sK[2][64 * 64];
    __shared__ u16 sVt[2][64 * 64];
    const int NQT = TSEQ / 128;                  // 16 q-tiles
    const int qt = (NQT - 1) - (int)(blockIdx.x / BH);
    const int bh = blockIdx.x % BH;
    const int b = bh / HNUM, h = bh % HNUM;
    const int tid = threadIdx.x, lane = tid & 63, w = tid >> 6;
    const int g = lane >> 4, lq = lane & 15;
    const int q0 = qt * 128;
    const int qlo = q0 + w * 16;
    const u16* qbase = qb  + (size_t)bh * TSEQ * DHEAD;
    const u16* kbase = kb  + (size_t)bh * TSEQ * DHEAD;
    const u16* vbase = vtb + (size_t)bh * DHEAD * TSEQ;

    // Q fragment (B-operand): Q[qlo+lq][ks*32 + g*8 + e]  (0.125 pre-folded)
    bf16x8 qf[2];
    #pragma unroll
    for (int ks = 0; ks < 2; ++ks)
        qf[ks] = *(const bf16x8*)&qbase[(size_t)(qlo + lq) * DHEAD + ks * 32 + g * 8];

    f32x4 o[4] = {};
    float mx = -__builtin_inff(), ls = 0.f;

    // staging constants: thread stages one 16B chunk of K and one of Vt.
    const int srow = tid >> 3;                               // 0..63
    const int lcol = (((tid & 7) << 4) ^ ((srow & 7) << 4)) >> 1;  // swizzled u16 col

    auto STAGE = [&](int buf, int kt) {
        const int k0 = kt << 6;
        gload_lds(kbase + (size_t)(k0 + srow) * DHEAD + lcol, &sK[buf][tid * 8]);
        gload_lds(vbase + (size_t)srow * TSEQ + k0 + lcol,    &sVt[buf][tid * 8]);
    };

    const int nk = 2 * qt + 2;
    STAGE(0, 0);
    __syncthreads();
    for (int kt = 0; kt < nk; ++kt) {
        const int k0 = kt << 6;
        if (kt + 1 < nk) STAGE((kt + 1) & 1, kt + 1);   // prefetch overlaps compute
        if (k0 <= qlo + 15) {                            // wave-uniform skip
            const u16* cK = sK[kt & 1];
            const u16* cV = sVt[kt & 1];
            // S^T = K Q^T : lane holds q=lq, kpos = k0 + n*16 + g*4 + j
            f32x4 s[4];
            #pragma unroll
            for (int n = 0; n < 4; ++n) {
                s[n] = f32x4{0.f, 0.f, 0.f, 0.f};
                #pragma unroll
                for (int ks = 0; ks < 2; ++ks) {
                    int r = n * 16 + lq;
                    int lb = (r * 128 + (ks * 32 + g * 8) * 2) ^ ((r & 7) << 4);
                    bf16x8 kf = *(const bf16x8*)((const char*)cK + lb);
                    s[n] = MFMA16(kf, qf[ks], s[n]);
                }
            }
            // causal mask (only near-diagonal tiles)
            if (k0 + 63 > qlo) {
                const int qa = qlo + lq;
                #pragma unroll
                for (int n = 0; n < 4; ++n)
                    #pragma unroll
                    for (int j = 0; j < 4; ++j)
                        if (k0 + n * 16 + g * 4 + j > qa) s[n][j] = -__builtin_inff();
            }
            // online softmax: row q=lq; 16 in-lane + 2 cross-group shfls
            float tmax = s[0][0];
            #pragma unroll
            for (int n = 0; n < 4; ++n)
                #pragma unroll
                for (int j = 0; j < 4; ++j) tmax = fmaxf(tmax, s[n][j]);
            tmax = fmaxf(tmax, __shfl_xor(tmax, 16));
            tmax = fmaxf(tmax, __shfl_xor(tmax, 32));
            float mnew = fmaxf(mx, tmax);
            float sc = __expf(mx - mnew);
            mx = mnew;
            float rsum = 0.f;
            #pragma unroll
            for (int n = 0; n < 4; ++n)
                #pragma unroll
                for (int j = 0; j < 4; ++j) {
                    float p = __expf(s[n][j] - mnew);
                    s[n][j] = p;
                    rsum += p;
                }
            rsum += __shfl_xor(rsum, 16);
            rsum += __shfl_xor(rsum, 32);
            ls = ls * sc + rsum;
            // rescale O (O-layout rows q = g*4+j)
            #pragma unroll
            for (int j = 0; j < 4; ++j) {
                float scj = __shfl(sc, (lane & 48) | ((g << 2) + j));
                #pragma unroll
                for (int n = 0; n < 4; ++n) o[n][j] *= scj;
            }
            // pack P to bf16 pairs (k ascending within u32)
            unsigned apk[4], bpk[4];
            #pragma unroll
            for (int n = 0; n < 4; ++n) {
                apk[n] = cvtpk(s[n][0], s[n][1]);
                bpk[n] = cvtpk(s[n][2], s[n][3]);
            }
            // PV: redistribute P into A-frag layout via shfl, then MFMA
            const int s0l = lq + ((lane & 16) << 1);
            const bool hi = (lane & 32) != 0;
            #pragma unroll
            for (int ks = 0; ks < 2; ++ks) {
                unsigned A0  = (unsigned)__shfl((int)apk[2 * ks],     s0l);
                unsigned B0  = (unsigned)__shfl((int)bpk[2 * ks],     s0l);
                unsigned A1  = (unsigned)__shfl((int)apk[2 * ks + 1], s0l);
                unsigned B1  = (unsigned)__shfl((int)bpk[2 * ks + 1], s0l);
                unsigned A0h = (unsigned)__shfl((int)apk[2 * ks],     s0l + 16);
                unsigned B0h = (unsigned)__shfl((int)bpk[2 * ks],     s0l + 16);
                unsigned A1h = (unsigned)__shfl((int)apk[2 * ks + 1], s0l + 16);
                unsigned B1h = (unsigned)__shfl((int)bpk[2 * ks + 1], s0l + 16);
                union { unsigned u[4]; bf16x8 v; } pa;
                pa.u[0] = hi ? A1  : A0;
                pa.u[1] = hi ? B1  : B0;
                pa.u[2] = hi ? A1h : A0h;
                pa.u[3] = hi ? B1h : B0h;
                #pragma unroll
                for (int n = 0; n < 4; ++n) {
                    int d = n * 16 + lq;
                    int lb = (d * 128 + (ks * 32 + g * 8) * 2) ^ ((d & 7) << 4);
                    bf16x8 vf = *(const bf16x8*)((const char*)cV + lb);
                    o[n] = MFMA16(pa.v, vf, o[n]);
                }
            }
        }
        __syncthreads();
    }

    // epilogue: y[b, t, h*64 + d] bf16 ; O rows q = g*4+j, l lives at q=lq
    #pragma unroll
    for (int j = 0; j < 4; ++j) {
        float lj = __shfl(ls, (lane & 48) | ((g << 2) + j));
        float inv = 1.f / lj;
        const int t = qlo + g * 4 + j;
        #pragma unroll
        for (int n = 0; n < 4; ++n) {
            const int c = h * DHEAD + n * 16 + lq;
            yb[((size_t)b * TSEQ + t) * CDIM + c] = f2b(o[n][j] * inv);
        }
    }
}

extern "C" void kernel_launch(void* const* d_in, const int* in_sizes, int n_in,
                              void* d_out, int out_size, void* d_ws, size_t ws_size,
                              hipStream_t stream) {
    const float* x      = (const float*)d_in[0];
    const float* W_attn = (const float*)d_in[1];
    const float* b_attn = (const float*)d_in[2];
    const float* W_proj = (const float*)d_in[3];
    const float* b_proj = (const float*)d_in[4];
    float* out = (float*)d_out;

    // workspace layout (bf16 = u16). yb aliases xb (xb dead after GEMM1).
    u16* ws = (u16*)d_ws;
    u16* xb     = ws;                                   // [BTOT][CDIM]
    u16* yb     = xb;                                   // [BTOT][CDIM] (alias)
    u16* WattnT = xb     + (size_t)BTOT * CDIM;         // [NQKV][CDIM]
    u16* WprojT = WattnT + (size_t)NQKV * CDIM;         // [CDIM][CDIM]
    u16* qb     = WprojT + (size_t)CDIM * CDIM;         // [BH][TSEQ][DHEAD]
    u16* kb     = qb     + (size_t)BH * TSEQ * DHEAD;
    u16* vtb    = kb     + (size_t)BH * TSEQ * DHEAD;   // [BH][DHEAD][TSEQ]

    // 1) casts / transposes
    int n4 = BTOT * CDIM / 4;
    cast_f32_bf16<<<(n4 + 255) / 256, 256, 0, stream>>>(x, xb, n4);
    tcast<<<dim3(NQKV / 32, CDIM / 32), dim3(32, 8), 0, stream>>>(W_attn, WattnT, CDIM, NQKV);
    tcast<<<dim3(CDIM / 32, CDIM / 32), dim3(32, 8), 0, stream>>>(W_proj, WprojT, CDIM, CDIM);

    // 2) QKV projection + scatter
    gemm_bt<0><<<dim3(NQKV / 128, BTOT / 128), 256, 0, stream>>>(
        xb, WattnT, b_attn, qb, kb, vtb, nullptr, BTOT, NQKV, CDIM);

    // 3) causal flash attention (longest-first 1D grid)
    attn_fwd<<<dim3((TSEQ / 128) * BH), 512, 0, stream>>>(qb, kb, vtb, yb);

    // 4) output projection
    gemm_bt<1><<<dim3(CDIM / 128, BTOT / 128), 256, 0, stream>>>(
        yb, WprojT, b_proj, nullptr, nullptr, nullptr, out, BTOT, CDIM, CDIM);
}